// Round 1
// baseline (13078.729 us; speedup 1.0000x reference)
//
#include <hip/hip_runtime.h>

#define Bn 64
#define Cn 128
#define Hn 36
#define Wn 100
#define KSn 9

// ---------------- copy x -> buf ----------------
__global__ void __launch_bounds__(256) k_copy(const float4* __restrict__ s,
                                              float4* __restrict__ d, int n4) {
  int i = blockIdx.x * 256 + threadIdx.x;
  if (i < n4) d[i] = s[i];
}

// ---------------- H-direction step ----------------
// buf[b][co][hc][w] += relu( sum_{ci,k} buf[b][ci][hp][w+k-4] * wt[co][ci][k] )
// grid (Bn, Cn/8), block 128. prev row staged in LDS; weights via scalar loads.
__global__ void __launch_bounds__(128) k_hstep(float* __restrict__ buf,
                                               const float* __restrict__ wt,
                                               int hp, int hc) {
  __shared__ float prev[Cn][Wn + 8];
  const int b = blockIdx.x;
  const int cog = blockIdx.y;  // co group of 8
  const int t = threadIdx.x;   // 0..127

  // stage prev row (all ci) as float4: Cn * (Wn/4) = 3200 float4
  const float* rb = buf + ((size_t)b * Cn * Hn + hp) * Wn;
  for (int g = t; g < Cn * (Wn / 4); g += 128) {
    int ci = g / 25, wq = g % 25;
    float4 v = *(const float4*)(rb + (size_t)ci * Hn * Wn + wq * 4);
    *(float4*)&prev[ci][4 + wq * 4] = v;
  }
  // zero pads
  for (int g = t; g < Cn * 8; g += 128) {
    int ci = g >> 3, s = g & 7;
    prev[ci][(s < 4) ? s : (Wn + s)] = 0.f;  // 0..3 front, 104..107 back
  }
  __syncthreads();
  if (t >= Wn) return;

  float acc[8] = {0.f, 0.f, 0.f, 0.f, 0.f, 0.f, 0.f, 0.f};
  const float* wb = wt + (size_t)cog * 8 * Cn * KSn;
  for (int ci = 0; ci < Cn; ++ci) {
    float p[KSn];
#pragma unroll
    for (int k = 0; k < KSn; ++k) p[k] = prev[ci][t + k];
#pragma unroll
    for (int j = 0; j < 8; ++j) {
      const float* w9 = wb + ((size_t)j * Cn + ci) * KSn;  // block-uniform -> s_load
#pragma unroll
      for (int k = 0; k < KSn; ++k) acc[j] = fmaf(p[k], w9[k], acc[j]);
    }
  }
  float* ob = buf + ((size_t)(b * Cn + cog * 8) * Hn + hc) * Wn + t;
#pragma unroll
  for (int j = 0; j < 8; ++j) ob[(size_t)j * Hn * Wn] += fmaxf(acc[j], 0.f);
}

// ---------------- transpose [b][c][h][w] -> [b][c][w][h] ----------------
__global__ void __launch_bounds__(256) k_t_hw2wh(const float* __restrict__ in,
                                                 float* __restrict__ out) {
  __shared__ float tile[Hn][Wn + 1];  // stride 101: bank-conflict-free
  const int bc = blockIdx.x;
  const float* ib = in + (size_t)bc * Hn * Wn;
  float* ob = out + (size_t)bc * Hn * Wn;
  for (int f = threadIdx.x; f < Hn * Wn; f += 256) tile[f / Wn][f % Wn] = ib[f];
  __syncthreads();
  for (int f = threadIdx.x; f < Hn * Wn; f += 256) {
    int w = f / Hn, h = f % Hn;
    ob[f] = tile[h][w];
  }
}

// ---------------- transpose back [b][c][w][h] -> [b][c][h][w] ----------------
__global__ void __launch_bounds__(256) k_t_wh2hw(const float* __restrict__ in,
                                                 float* __restrict__ out) {
  __shared__ float tile[Hn][Wn + 1];
  const int bc = blockIdx.x;
  const float* ib = in + (size_t)bc * Hn * Wn;
  float* ob = out + (size_t)bc * Hn * Wn;
  for (int f = threadIdx.x; f < Hn * Wn; f += 256) {
    int w = f / Hn, h = f % Hn;
    tile[h][w] = ib[f];
  }
  __syncthreads();
  for (int f = threadIdx.x; f < Hn * Wn; f += 256) ob[f] = tile[f / Wn][f % Wn];
}

// ---------------- W-direction step on transposed layout [b][c][w][h] ----------------
// tb[b][co][wc][h] += relu( sum_{ci,k} tb[b][ci][wp][h+k-4] * wt[co][ci][k] )
// grid (Bn, Cn/8), block 128 (2 waves; wave0 -> co j 0..3, wave1 -> j 4..7).
__global__ void __launch_bounds__(128) k_wstep_t(float* __restrict__ tb,
                                                 const float* __restrict__ wt,
                                                 int wp, int wc) {
  __shared__ float prev[Cn][Hn + 8];
  const int b = blockIdx.x;
  const int cog = blockIdx.y;
  const int t = threadIdx.x;
  const int h = t & 63;
  const int jb = __builtin_amdgcn_readfirstlane((t >> 6) * 4);  // wave-uniform

  const float* cb = tb + ((size_t)b * Cn * Wn + wp) * Hn;
  for (int g = t; g < Cn * (Hn / 4); g += 128) {  // 1152 float4
    int ci = g / 9, hq = g % 9;
    float4 v = *(const float4*)(cb + (size_t)ci * Wn * Hn + hq * 4);
    *(float4*)&prev[ci][4 + hq * 4] = v;
  }
  for (int g = t; g < Cn * 8; g += 128) {
    int ci = g >> 3, s = g & 7;
    prev[ci][(s < 4) ? s : (Hn + s)] = 0.f;
  }
  __syncthreads();
  if (h >= Hn) return;

  float acc[4] = {0.f, 0.f, 0.f, 0.f};
  const float* wb = wt + (size_t)(cog * 8 + jb) * Cn * KSn;
  for (int ci = 0; ci < Cn; ++ci) {
    float p[KSn];
#pragma unroll
    for (int k = 0; k < KSn; ++k) p[k] = prev[ci][h + k];
#pragma unroll
    for (int j = 0; j < 4; ++j) {
      const float* w9 = wb + ((size_t)j * Cn + ci) * KSn;  // wave-uniform -> s_load
#pragma unroll
      for (int k = 0; k < KSn; ++k) acc[j] = fmaf(p[k], w9[k], acc[j]);
    }
  }
  float* ob = tb + ((size_t)(b * Cn + cog * 8 + jb) * Wn + wc) * Hn + h;
#pragma unroll
  for (int j = 0; j < 4; ++j) ob[(size_t)j * Wn * Hn] += fmaxf(acc[j], 0.f);
}

// ---------------- W-direction step, direct (fallback if d_ws too small) ----------------
__global__ void __launch_bounds__(128) k_wstep_d(float* __restrict__ buf,
                                                 const float* __restrict__ wt,
                                                 int wp, int wc) {
  __shared__ float prev[Cn][Hn + 8];
  const int b = blockIdx.x;
  const int cog = blockIdx.y;
  const int t = threadIdx.x;
  const int h = t & 63;
  const int jb = __builtin_amdgcn_readfirstlane((t >> 6) * 4);

  for (int g = t; g < Cn * Hn; g += 128) {  // strided gather
    int ci = g / Hn, hh = g % Hn;
    prev[ci][4 + hh] = buf[((size_t)(b * Cn + ci) * Hn + hh) * Wn + wp];
  }
  for (int g = t; g < Cn * 8; g += 128) {
    int ci = g >> 3, s = g & 7;
    prev[ci][(s < 4) ? s : (Hn + s)] = 0.f;
  }
  __syncthreads();
  if (h >= Hn) return;

  float acc[4] = {0.f, 0.f, 0.f, 0.f};
  const float* wb = wt + (size_t)(cog * 8 + jb) * Cn * KSn;
  for (int ci = 0; ci < Cn; ++ci) {
    float p[KSn];
#pragma unroll
    for (int k = 0; k < KSn; ++k) p[k] = prev[ci][h + k];
#pragma unroll
    for (int j = 0; j < 4; ++j) {
      const float* w9 = wb + ((size_t)j * Cn + ci) * KSn;
#pragma unroll
      for (int k = 0; k < KSn; ++k) acc[j] = fmaf(p[k], w9[k], acc[j]);
    }
  }
  float* ob = buf + ((size_t)(b * Cn + cog * 8 + jb) * Hn + h) * Wn + wc;
#pragma unroll
  for (int j = 0; j < 4; ++j) ob[(size_t)j * Hn * Wn] += fmaxf(acc[j], 0.f);
}

extern "C" void kernel_launch(void* const* d_in, const int* in_sizes, int n_in,
                              void* d_out, int out_size, void* d_ws, size_t ws_size,
                              hipStream_t stream) {
  const float* x  = (const float*)d_in[0];
  const float* wd = (const float*)d_in[1];
  const float* wu = (const float*)d_in[2];
  const float* wr = (const float*)d_in[3];
  const float* wl = (const float*)d_in[4];
  float* buf = (float*)d_out;
  const size_t nelem = (size_t)Bn * Cn * Hn * Wn;  // 29,491,200

  // buf <- x
  k_copy<<<(int)(nelem / 4 + 255) / 256, 256, 0, stream>>>(
      (const float4*)x, (float4*)buf, (int)(nelem / 4));

  dim3 grid8(Bn, Cn / 8);

  // down: h = 1..H-1, prev = h-1
  for (int hh = 1; hh < Hn; ++hh)
    k_hstep<<<grid8, 128, 0, stream>>>(buf, wd, hh - 1, hh);
  // up: h = H-2..0, prev = h+1
  for (int hh = Hn - 2; hh >= 0; --hh)
    k_hstep<<<grid8, 128, 0, stream>>>(buf, wu, hh + 1, hh);

  const bool use_t = (ws_size >= nelem * sizeof(float));
  if (use_t) {
    float* tb = (float*)d_ws;
    k_t_hw2wh<<<Bn * Cn, 256, 0, stream>>>(buf, tb);
    for (int ww = 1; ww < Wn; ++ww)
      k_wstep_t<<<grid8, 128, 0, stream>>>(tb, wr, ww - 1, ww);
    for (int ww = Wn - 2; ww >= 0; --ww)
      k_wstep_t<<<grid8, 128, 0, stream>>>(tb, wl, ww + 1, ww);
    k_t_wh2hw<<<Bn * Cn, 256, 0, stream>>>(tb, buf);
  } else {
    for (int ww = 1; ww < Wn; ++ww)
      k_wstep_d<<<grid8, 128, 0, stream>>>(buf, wr, ww - 1, ww);
    for (int ww = Wn - 2; ww >= 0; --ww)
      k_wstep_d<<<grid8, 128, 0, stream>>>(buf, wl, ww + 1, ww);
  }
}